// Round 3
// 260.782 us; speedup vs baseline: 1.2427x; 1.2427x over previous
//
#include <hip/hip_runtime.h>
#include <hip/hip_fp16.h>

#define N_NODES 100000
#define N_EDGES 1250000
#define F 64
#define SCAN_CHUNK 1024
#define NBLK_SCAN ((N_NODES + SCAN_CHUNK - 1) / SCAN_CHUNK)  // 98
#define GPW 4    // nodes per wave
#define NPB 32   // nodes per block (8 waves * GPW)
#define TP  33   // tile pad: column writes (lane*33+n)%32 = (lane+n)%32 -> conflict-free

// ---------------- CSR-build path ----------------

// K1: histogram of receivers + per-edge rank within receiver.
// The atomic return value IS the rank -> permute needs no atomic at all.
__global__ __launch_bounds__(256) void hist_kernel(const int* __restrict__ ei,
                                                   int* __restrict__ counts,
                                                   int* __restrict__ rank) {
    int e = blockIdx.x * 256 + threadIdx.x;
    if (e < N_EDGES) rank[e] = atomicAdd(&counts[ei[N_EDGES + e]], 1);
}

// K2a: per-1024-chunk partial sums of counts.
__global__ __launch_bounds__(256) void scan_reduce_kernel(const int* __restrict__ counts,
                                                          int* __restrict__ partials) {
    int base = blockIdx.x * SCAN_CHUNK + threadIdx.x * 4;
    int s = 0;
    if (base + 3 < N_NODES) {
        int4 c = *(const int4*)&counts[base];
        s = c.x + c.y + c.z + c.w;
    }
    for (int d = 32; d > 0; d >>= 1) s += __shfl_down(s, d);
    __shared__ int lds[4];
    int lane = threadIdx.x & 63, wave = threadIdx.x >> 6;
    if (lane == 0) lds[wave] = s;
    __syncthreads();
    if (threadIdx.x == 0) partials[blockIdx.x] = lds[0] + lds[1] + lds[2] + lds[3];
}

// K2b: per-chunk exclusive scan; chunk base reduced in-block from raw partials.
__global__ __launch_bounds__(256) void scan_apply_kernel(const int* __restrict__ counts,
                                                         const int* __restrict__ partials,
                                                         int* __restrict__ off) {
    __shared__ int sh_red[4];
    __shared__ int sh_base;
    __shared__ int wsum[4];
    int t = threadIdx.x;
    int lane = t & 63, wave = t >> 6;

    int pp = 0;
    if (t < blockIdx.x && t < NBLK_SCAN) pp = partials[t];
    for (int d = 32; d > 0; d >>= 1) pp += __shfl_down(pp, d);
    if (lane == 0) sh_red[wave] = pp;
    __syncthreads();
    if (t == 0) sh_base = sh_red[0] + sh_red[1] + sh_red[2] + sh_red[3];

    int base = blockIdx.x * SCAN_CHUNK + t * 4;
    int4 c = {0, 0, 0, 0};
    bool act = (base + 3 < N_NODES);
    if (act) c = *(const int4*)&counts[base];
    int s = c.x + c.y + c.z + c.w;

    int xs = s;
    for (int d = 1; d < 64; d <<= 1) {
        int y = __shfl_up(xs, d);
        if (lane >= d) xs += y;
    }
    if (lane == 63) wsum[wave] = xs;
    __syncthreads();
    int pre = xs - s;
    for (int w = 0; w < wave; ++w) pre += wsum[w];
    pre += sh_base;

    if (act) {
        int o0 = pre, o1 = o0 + c.x, o2 = o1 + c.y, o3 = o2 + c.z;
        int4 o = {o0, o1, o2, o3};
        *(int4*)&off[base] = o;
        if (base + 4 == N_NODES) off[N_NODES] = o3 + c.w;  // == N_EDGES
    }
}

// K3: scatter packed payload {src:int, (w0,w1):half2} -> ONE 8B store per edge.
// Atomic-free: pos = off[r] + rank[e]. off is read-only (replicates in every
// XCD L2); rank load is coalesced. Only the 8B payload store is scattered.
__global__ __launch_bounds__(256) void permute_kernel(const int* __restrict__ ei,
                                                      const float* __restrict__ ew,
                                                      const int* __restrict__ off,
                                                      const int* __restrict__ rank,
                                                      int2* __restrict__ pay) {
    int e = blockIdx.x * 256 + threadIdx.x;
    if (e >= N_EDGES) return;
    int r = ei[N_EDGES + e];
    int pos = off[r] + rank[e];
    __half2 h = __floats2half2_rn(ew[e], ew[N_EDGES + e]);
    int2 p;
    p.x = ei[e];
    p.y = *(const int*)&h;
    pay[pos] = p;
}

// K4: fused aggregation + GEMM. 512 threads = 8 waves x GPW=4 nodes = 32 nodes/block.
// Edge loop (contiguous CSR spans, x4 batched with next-batch prefetch)
// flushes agg rows into transposed LDS tiles [k][n] (pad 33 -> conflict-free column
// writes). After one barrier, 256 threads do the register-tiled 4n x 4j GEMM per
// direction (A from LDS, W/bias from global/L1) and write final out coalesced.
__global__ __launch_bounds__(512, 4) void agg_gemm_kernel(
    const float* __restrict__ x, const int* __restrict__ off,
    const int2* __restrict__ pay,
    const float* __restrict__ Wsrc, const float* __restrict__ Wdst,
    const float* __restrict__ bsrc, const float* __restrict__ bdst,
    float* __restrict__ outA, float* __restrict__ outB)
{
    __shared__ float tA[F * TP];
    __shared__ float tB[F * TP];
    int t = threadIdx.x;
    int w = t >> 6;        // wave in block: 0..7
    int lane = t & 63;     // feature k
    int n0 = blockIdx.x * NPB + w * GPW;
    int nIB0 = w * GPW;

    int b[GPW + 1];
    #pragma unroll
    for (int j = 0; j <= GPW; ++j) b[j] = off[n0 + j];

    int i = b[0];
    const int end = b[GPW];
    int cur = 0;
    int next_b = b[1];
    float accA = 0.f, accB = 0.f;

#define FLUSH() { tA[lane * TP + nIB0 + cur] = accA;                  \
                  tB[lane * TP + nIB0 + cur] = accB;                  \
                  accA = 0.f; accB = 0.f; ++cur;                      \
                  next_b = (cur < GPW) ? b[cur + 1] : 0x7fffffff; }

    int2 pc[4]; float vc[4];
    if (i + 4 <= end) {
        #pragma unroll
        for (int j = 0; j < 4; ++j) pc[j] = pay[i + j];
        #pragma unroll
        for (int j = 0; j < 4; ++j) vc[j] = x[(size_t)pc[j].x * F + lane];
    }
    while (i + 8 <= end) {
        int2 pn[4]; float vn[4];
        #pragma unroll
        for (int j = 0; j < 4; ++j) pn[j] = pay[i + 4 + j];
        #pragma unroll
        for (int j = 0; j < 4; ++j) vn[j] = x[(size_t)pn[j].x * F + lane];
        #pragma unroll
        for (int j = 0; j < 4; ++j) {
            while (i + j == next_b) FLUSH();
            float2 wv = __half22float2(*(const __half2*)&pc[j].y);
            accA += vc[j] * wv.x; accB += vc[j] * wv.y;
        }
        i += 4;
        #pragma unroll
        for (int j = 0; j < 4; ++j) { pc[j] = pn[j]; vc[j] = vn[j]; }
    }
    if (i + 4 <= end) {
        #pragma unroll
        for (int j = 0; j < 4; ++j) {
            while (i + j == next_b) FLUSH();
            float2 wv = __half22float2(*(const __half2*)&pc[j].y);
            accA += vc[j] * wv.x; accB += vc[j] * wv.y;
        }
        i += 4;
    }
    while (i < end) {
        while (i == next_b) FLUSH();
        int2 p = pay[i];
        float2 wv = __half22float2(*(const __half2*)&p.y);
        float v = x[(size_t)p.x * F + lane];
        accA += v * wv.x; accB += v * wv.y;
        ++i;
    }
    while (cur < GPW) FLUSH();
#undef FLUSH

    __syncthreads();

    // GEMM phase: 256 active threads; dir = t>>7; 4 nodes x 4 feats per thread.
    if (t < 256) {
        int dir = t >> 7;
        int tx = t & 15, ty = (t >> 4) & 7;
        int j4 = tx * 4, n4 = ty * 4;
        const float* W    = dir ? Wdst : Wsrc;
        const float* bias = dir ? bdst : bsrc;
        const float* tile = dir ? tB : tA;
        float* out        = dir ? outB : outA;

        float4 bj = *(const float4*)&bias[j4];
        float4 a0 = bj, a1 = bj, a2 = bj, a3 = bj;
        #pragma unroll 8
        for (int k = 0; k < F; ++k) {
            float4 wv = *(const float4*)&W[k * F + j4];
            float v0 = tile[k * TP + n4 + 0];
            float v1 = tile[k * TP + n4 + 1];
            float v2 = tile[k * TP + n4 + 2];
            float v3 = tile[k * TP + n4 + 3];
            a0.x += v0 * wv.x; a0.y += v0 * wv.y; a0.z += v0 * wv.z; a0.w += v0 * wv.w;
            a1.x += v1 * wv.x; a1.y += v1 * wv.y; a1.z += v1 * wv.z; a1.w += v1 * wv.w;
            a2.x += v2 * wv.x; a2.y += v2 * wv.y; a2.z += v2 * wv.z; a2.w += v2 * wv.w;
            a3.x += v3 * wv.x; a3.y += v3 * wv.y; a3.z += v3 * wv.z; a3.w += v3 * wv.w;
        }
        int nb = blockIdx.x * NPB + n4;
        *(float4*)&out[(size_t)(nb + 0) * F + j4] = a0;
        *(float4*)&out[(size_t)(nb + 1) * F + j4] = a1;
        *(float4*)&out[(size_t)(nb + 2) * F + j4] = a2;
        *(float4*)&out[(size_t)(nb + 3) * F + j4] = a3;
    }
}

// ---------------- fallback path (round-1 atomic version) ----------------

__global__ __launch_bounds__(256) void scatter_fallback(const float4* __restrict__ x4,
                                                        const int* __restrict__ ei,
                                                        const float* __restrict__ ew,
                                                        float* __restrict__ aggA,
                                                        float* __restrict__ aggB) {
    int t = blockIdx.x * blockDim.x + threadIdx.x;
    int e = t >> 4;
    int lane16 = t & 15;
    if (e >= N_EDGES) return;
    int src = ei[e], dst = ei[N_EDGES + e];
    float w0 = ew[e], w1 = ew[N_EDGES + e];
    float4 v = x4[(size_t)src * 16 + lane16];
    int base = dst * F + lane16 * 4;
    atomicAdd(&aggA[base + 0], v.x * w0); atomicAdd(&aggA[base + 1], v.y * w0);
    atomicAdd(&aggA[base + 2], v.z * w0); atomicAdd(&aggA[base + 3], v.w * w0);
    atomicAdd(&aggB[base + 0], v.x * w1); atomicAdd(&aggB[base + 1], v.y * w1);
    atomicAdd(&aggB[base + 2], v.z * w1); atomicAdd(&aggB[base + 3], v.w * w1);
}

__global__ __launch_bounds__(256) void matmul_fallback(float* __restrict__ outA, float* __restrict__ outB,
                                                       const float* __restrict__ Wsrc, const float* __restrict__ Wdst,
                                                       const float* __restrict__ bsrc, const float* __restrict__ bdst) {
    __shared__ float lWs[F * F];
    __shared__ float lWd[F * F];
    for (int i = threadIdx.x; i < F * F / 4; i += blockDim.x) {
        ((float4*)lWs)[i] = ((const float4*)Wsrc)[i];
        ((float4*)lWd)[i] = ((const float4*)Wdst)[i];
    }
    __syncthreads();
    int wave = (blockIdx.x * blockDim.x + threadIdx.x) >> 6;
    int lane = threadIdx.x & 63;
    if (wave >= N_NODES) return;
    size_t rowbase = (size_t)wave * F;
    float a0 = outA[rowbase + lane], a1 = outB[rowbase + lane];
    float acc0 = bsrc[lane], acc1 = bdst[lane];
    #pragma unroll
    for (int k = 0; k < F; ++k) {
        acc0 += __shfl(a0, k) * lWs[k * F + lane];
        acc1 += __shfl(a1, k) * lWd[k * F + lane];
    }
    outA[rowbase + lane] = acc0;
    outB[rowbase + lane] = acc1;
}

// ---------------- launch ----------------

extern "C" void kernel_launch(void* const* d_in, const int* in_sizes, int n_in,
                              void* d_out, int out_size, void* d_ws, size_t ws_size,
                              hipStream_t stream) {
    const float* x    = (const float*)d_in[0];
    const int*   ei   = (const int*)d_in[1];
    const float* ew   = (const float*)d_in[2];
    const float* Wsrc = (const float*)d_in[3];
    const float* Wdst = (const float*)d_in[4];
    const float* bsrc = (const float*)d_in[5];
    const float* bdst = (const float*)d_in[6];

    float* outA = (float*)d_out;
    float* outB = (float*)d_out + (size_t)N_NODES * F;

    // ws layout (8B-aligned segments)
    const size_t OFF_COUNTS   = 0;         // N*4      = 400000 -> pad 400128
    const size_t OFF_OFF      = 400128;    // (N+1)*4  = 400004 -> pad 400512
    const size_t OFF_PARTIALS = 800640;    // 512
    const size_t OFF_RANK     = 801152;    // E*4 = 5,000,000
    const size_t OFF_PAY      = 5801152;   // E*8 = 10,000,000
    const size_t REQ          = 15801152;

    if (ws_size >= REQ) {
        char* ws = (char*)d_ws;
        int*  counts   = (int*)(ws + OFF_COUNTS);
        int*  off      = (int*)(ws + OFF_OFF);
        int*  partials = (int*)(ws + OFF_PARTIALS);
        int*  rank     = (int*)(ws + OFF_RANK);
        int2* pay      = (int2*)(ws + OFF_PAY);

        hipMemsetAsync(counts, 0, (size_t)N_NODES * sizeof(int), stream);

        int eblk = (N_EDGES + 255) / 256;  // 4883
        hist_kernel<<<eblk, 256, 0, stream>>>(ei, counts, rank);
        scan_reduce_kernel<<<NBLK_SCAN, 256, 0, stream>>>(counts, partials);
        scan_apply_kernel<<<NBLK_SCAN, 256, 0, stream>>>(counts, partials, off);
        permute_kernel<<<eblk, 256, 0, stream>>>(ei, ew, off, rank, pay);
        agg_gemm_kernel<<<N_NODES / NPB, 512, 0, stream>>>(
            x, off, pay, Wsrc, Wdst, bsrc, bdst, outA, outB);
    } else {
        hipMemsetAsync(d_out, 0, (size_t)out_size * sizeof(float), stream);
        int blocks_scatter = (N_EDGES * 16 + 255) / 256;
        scatter_fallback<<<blocks_scatter, 256, 0, stream>>>((const float4*)x, ei, ew, outA, outB);
        int blocks_mm = (N_NODES * 64 + 255) / 256;
        matmul_fallback<<<blocks_mm, 256, 0, stream>>>(outA, outB, Wsrc, Wdst, bsrc, bdst);
    }
}

// Round 4
// 255.898 us; speedup vs baseline: 1.2664x; 1.0191x over previous
//
#include <hip/hip_runtime.h>
#include <hip/hip_fp16.h>

#define N_NODES 100000
#define N_EDGES 1250000
#define F 64
#define SCAN_CHUNK 1024
#define NBLK_SCAN ((N_NODES + SCAN_CHUNK - 1) / SCAN_CHUNK)  // 98
#define NPB 16   // nodes per block: 4 waves x 4 groups(16 lanes) = 16 nodes
#define TP 18    // tile leading pad: keeps (k*TP+n)*4 8B-aligned for float2 reads

// ---------------- CSR-build path ----------------

// K1: histogram of receivers + per-edge rank within receiver.
// The atomic return value IS the rank -> permute needs no atomic at all.
__global__ __launch_bounds__(256) void hist_kernel(const int* __restrict__ ei,
                                                   int* __restrict__ counts,
                                                   int* __restrict__ rank) {
    int e = blockIdx.x * 256 + threadIdx.x;
    if (e < N_EDGES) rank[e] = atomicAdd(&counts[ei[N_EDGES + e]], 1);
}

// K2a: per-1024-chunk partial sums of counts.
__global__ __launch_bounds__(256) void scan_reduce_kernel(const int* __restrict__ counts,
                                                          int* __restrict__ partials) {
    int base = blockIdx.x * SCAN_CHUNK + threadIdx.x * 4;
    int s = 0;
    if (base + 3 < N_NODES) {
        int4 c = *(const int4*)&counts[base];
        s = c.x + c.y + c.z + c.w;
    }
    for (int d = 32; d > 0; d >>= 1) s += __shfl_down(s, d);
    __shared__ int lds[4];
    int lane = threadIdx.x & 63, wave = threadIdx.x >> 6;
    if (lane == 0) lds[wave] = s;
    __syncthreads();
    if (threadIdx.x == 0) partials[blockIdx.x] = lds[0] + lds[1] + lds[2] + lds[3];
}

// K2b: per-chunk exclusive scan; chunk base reduced in-block from raw partials.
__global__ __launch_bounds__(256) void scan_apply_kernel(const int* __restrict__ counts,
                                                         const int* __restrict__ partials,
                                                         int* __restrict__ off) {
    __shared__ int sh_red[4];
    __shared__ int sh_base;
    __shared__ int wsum[4];
    int t = threadIdx.x;
    int lane = t & 63, wave = t >> 6;

    int pp = 0;
    if (t < blockIdx.x && t < NBLK_SCAN) pp = partials[t];
    for (int d = 32; d > 0; d >>= 1) pp += __shfl_down(pp, d);
    if (lane == 0) sh_red[wave] = pp;
    __syncthreads();
    if (t == 0) sh_base = sh_red[0] + sh_red[1] + sh_red[2] + sh_red[3];

    int base = blockIdx.x * SCAN_CHUNK + t * 4;
    int4 c = {0, 0, 0, 0};
    bool act = (base + 3 < N_NODES);
    if (act) c = *(const int4*)&counts[base];
    int s = c.x + c.y + c.z + c.w;

    int xs = s;
    for (int d = 1; d < 64; d <<= 1) {
        int y = __shfl_up(xs, d);
        if (lane >= d) xs += y;
    }
    if (lane == 63) wsum[wave] = xs;
    __syncthreads();
    int pre = xs - s;
    for (int w = 0; w < wave; ++w) pre += wsum[w];
    pre += sh_base;

    if (act) {
        int o0 = pre, o1 = o0 + c.x, o2 = o1 + c.y, o3 = o2 + c.z;
        int4 o = {o0, o1, o2, o3};
        *(int4*)&off[base] = o;
        if (base + 4 == N_NODES) off[N_NODES] = o3 + c.w;  // == N_EDGES
    }
}

// K3: scatter packed payload {src:int, (w0,w1):half2} -> ONE 8B store per edge.
// Atomic-free: pos = off[r] + rank[e].
__global__ __launch_bounds__(256) void permute_kernel(const int* __restrict__ ei,
                                                      const float* __restrict__ ew,
                                                      const int* __restrict__ off,
                                                      const int* __restrict__ rank,
                                                      int2* __restrict__ pay) {
    int e = blockIdx.x * 256 + threadIdx.x;
    if (e >= N_EDGES) return;
    int r = ei[N_EDGES + e];
    int pos = off[r] + rank[e];
    __half2 h = __floats2half2_rn(ew[e], ew[N_EDGES + e]);
    int2 p;
    p.x = ei[e];
    p.y = *(const int*)&h;
    pay[pos] = p;
}

// K4: fused aggregation + GEMM, restructured for ILP + occupancy.
// 256 threads = 4 waves x 4 groups of 16 lanes. Each 16-lane group owns ONE
// node; lane l4 holds features [4*l4, 4*l4+4) as a float4 accumulator.
// Edge loop: per step one broadcast pay load (8B) + one coalesced 256B x-row
// load + 8 FMA, with a 2-deep rolling prefetch (two x-rows in flight per
// group). No flush logic, no cross-group reduce; one LDS write at the end.
// GEMM phase: ALL 256 threads, 2 nodes x 4 feats each, ds_read_b64 tile reads.
__global__ __launch_bounds__(256, 8) void agg_gemm_kernel(
    const float* __restrict__ x, const int* __restrict__ off,
    const int2* __restrict__ pay,
    const float* __restrict__ Wsrc, const float* __restrict__ Wdst,
    const float* __restrict__ bsrc, const float* __restrict__ bdst,
    float* __restrict__ outA, float* __restrict__ outB)
{
    __shared__ float tA[F * TP];
    __shared__ float tB[F * TP];
    int t = threadIdx.x;
    int w = t >> 6;          // wave 0..3
    int lane = t & 63;
    int g = lane >> 4;       // group in wave 0..3
    int l4 = lane & 15;      // feat4 index 0..15
    int nIB = w * 4 + g;     // node in block 0..15
    int n = blockIdx.x * NPB + nIB;

    const float4* x4 = (const float4*)x;
    int beg = off[n];
    int end = off[n + 1];

    float4 accA = {0.f, 0.f, 0.f, 0.f};
    float4 accB = {0.f, 0.f, 0.f, 0.f};

    if (beg < end) {
        int last = end - 1;
        // 2-deep rolling pipeline; index clamp keeps loads branch-free & valid.
        int2 p0 = pay[beg];
        float4 x0 = x4[(size_t)p0.x * 16 + l4];
        int i1 = min(beg + 1, last);
        int2 p1 = pay[i1];
        float4 x1 = x4[(size_t)p1.x * 16 + l4];
        for (int i = beg; i < end; ++i) {
            int i2 = min(i + 2, last);
            int2 p2 = pay[i2];
            float4 x2 = x4[(size_t)p2.x * 16 + l4];
            float2 wv = __half22float2(*(const __half2*)&p0.y);
            accA.x += x0.x * wv.x; accA.y += x0.y * wv.x;
            accA.z += x0.z * wv.x; accA.w += x0.w * wv.x;
            accB.x += x0.x * wv.y; accB.y += x0.y * wv.y;
            accB.z += x0.z * wv.y; accB.w += x0.w * wv.y;
            p0 = p1; x0 = x1;
            p1 = p2; x1 = x2;
        }
    }

    // Transposed LDS tile write: tA[feat][node]. Addr (4*l4+c)*TP + nIB;
    // across the wave banks are 2-way (free) at worst.
    #pragma unroll
    for (int c = 0; c < 4; ++c) {
        tA[(4 * l4 + c) * TP + nIB] = ((const float*)&accA)[c];
        tB[(4 * l4 + c) * TP + nIB] = ((const float*)&accB)[c];
    }

    __syncthreads();

    // GEMM phase: 256 threads, dir = t>>7; per dir 128 threads cover
    // 16 nodes x 64 feats as 2 nodes x 4 feats per thread.
    int dir = t >> 7;
    int tx = t & 15;           // feat group: j4 = 4*tx
    int ty = (t >> 4) & 7;     // node pair:  n2 = 2*ty
    const float* W    = dir ? Wdst : Wsrc;
    const float* bias = dir ? bdst : bsrc;
    const float* tile = dir ? tB : tA;
    float* out        = dir ? outB : outA;
    int j4 = tx * 4, n2 = ty * 2;

    float4 bj = *(const float4*)&bias[j4];
    float4 a0 = bj, a1 = bj;
    #pragma unroll 8
    for (int k = 0; k < F; ++k) {
        float4 wv = *(const float4*)&W[k * F + j4];
        float2 v  = *(const float2*)&tile[k * TP + n2];   // 8B-aligned (TP even)
        a0.x += v.x * wv.x; a0.y += v.x * wv.y; a0.z += v.x * wv.z; a0.w += v.x * wv.w;
        a1.x += v.y * wv.x; a1.y += v.y * wv.y; a1.z += v.y * wv.z; a1.w += v.y * wv.w;
    }
    int nb = blockIdx.x * NPB + n2;
    *(float4*)&out[(size_t)(nb + 0) * F + j4] = a0;
    *(float4*)&out[(size_t)(nb + 1) * F + j4] = a1;
}

// ---------------- fallback path (round-1 atomic version) ----------------

__global__ __launch_bounds__(256) void scatter_fallback(const float4* __restrict__ x4,
                                                        const int* __restrict__ ei,
                                                        const float* __restrict__ ew,
                                                        float* __restrict__ aggA,
                                                        float* __restrict__ aggB) {
    int t = blockIdx.x * blockDim.x + threadIdx.x;
    int e = t >> 4;
    int lane16 = t & 15;
    if (e >= N_EDGES) return;
    int src = ei[e], dst = ei[N_EDGES + e];
    float w0 = ew[e], w1 = ew[N_EDGES + e];
    float4 v = x4[(size_t)src * 16 + lane16];
    int base = dst * F + lane16 * 4;
    atomicAdd(&aggA[base + 0], v.x * w0); atomicAdd(&aggA[base + 1], v.y * w0);
    atomicAdd(&aggA[base + 2], v.z * w0); atomicAdd(&aggA[base + 3], v.w * w0);
    atomicAdd(&aggB[base + 0], v.x * w1); atomicAdd(&aggB[base + 1], v.y * w1);
    atomicAdd(&aggB[base + 2], v.z * w1); atomicAdd(&aggB[base + 3], v.w * w1);
}

__global__ __launch_bounds__(256) void matmul_fallback(float* __restrict__ outA, float* __restrict__ outB,
                                                       const float* __restrict__ Wsrc, const float* __restrict__ Wdst,
                                                       const float* __restrict__ bsrc, const float* __restrict__ bdst) {
    __shared__ float lWs[F * F];
    __shared__ float lWd[F * F];
    for (int i = threadIdx.x; i < F * F / 4; i += blockDim.x) {
        ((float4*)lWs)[i] = ((const float4*)Wsrc)[i];
        ((float4*)lWd)[i] = ((const float4*)Wdst)[i];
    }
    __syncthreads();
    int wave = (blockIdx.x * blockDim.x + threadIdx.x) >> 6;
    int lane = threadIdx.x & 63;
    if (wave >= N_NODES) return;
    size_t rowbase = (size_t)wave * F;
    float a0 = outA[rowbase + lane], a1 = outB[rowbase + lane];
    float acc0 = bsrc[lane], acc1 = bdst[lane];
    #pragma unroll
    for (int k = 0; k < F; ++k) {
        acc0 += __shfl(a0, k) * lWs[k * F + lane];
        acc1 += __shfl(a1, k) * lWd[k * F + lane];
    }
    outA[rowbase + lane] = acc0;
    outB[rowbase + lane] = acc1;
}

// ---------------- launch ----------------

extern "C" void kernel_launch(void* const* d_in, const int* in_sizes, int n_in,
                              void* d_out, int out_size, void* d_ws, size_t ws_size,
                              hipStream_t stream) {
    const float* x    = (const float*)d_in[0];
    const int*   ei   = (const int*)d_in[1];
    const float* ew   = (const float*)d_in[2];
    const float* Wsrc = (const float*)d_in[3];
    const float* Wdst = (const float*)d_in[4];
    const float* bsrc = (const float*)d_in[5];
    const float* bdst = (const float*)d_in[6];

    float* outA = (float*)d_out;
    float* outB = (float*)d_out + (size_t)N_NODES * F;

    // ws layout (8B-aligned segments)
    const size_t OFF_COUNTS   = 0;         // N*4      = 400000 -> pad 400128
    const size_t OFF_OFF      = 400128;    // (N+1)*4  = 400004 -> pad 400512
    const size_t OFF_PARTIALS = 800640;    // 512
    const size_t OFF_RANK     = 801152;    // E*4 = 5,000,000
    const size_t OFF_PAY      = 5801152;   // E*8 = 10,000,000
    const size_t REQ          = 15801152;

    if (ws_size >= REQ) {
        char* ws = (char*)d_ws;
        int*  counts   = (int*)(ws + OFF_COUNTS);
        int*  off      = (int*)(ws + OFF_OFF);
        int*  partials = (int*)(ws + OFF_PARTIALS);
        int*  rank     = (int*)(ws + OFF_RANK);
        int2* pay      = (int2*)(ws + OFF_PAY);

        hipMemsetAsync(counts, 0, (size_t)N_NODES * sizeof(int), stream);

        int eblk = (N_EDGES + 255) / 256;  // 4883
        hist_kernel<<<eblk, 256, 0, stream>>>(ei, counts, rank);
        scan_reduce_kernel<<<NBLK_SCAN, 256, 0, stream>>>(counts, partials);
        scan_apply_kernel<<<NBLK_SCAN, 256, 0, stream>>>(counts, partials, off);
        permute_kernel<<<eblk, 256, 0, stream>>>(ei, ew, off, rank, pay);
        agg_gemm_kernel<<<N_NODES / NPB, 256, 0, stream>>>(
            x, off, pay, Wsrc, Wdst, bsrc, bdst, outA, outB);
    } else {
        hipMemsetAsync(d_out, 0, (size_t)out_size * sizeof(float), stream);
        int blocks_scatter = (N_EDGES * 16 + 255) / 256;
        scatter_fallback<<<blocks_scatter, 256, 0, stream>>>((const float4*)x, ei, ew, outA, outB);
        int blocks_mm = (N_NODES * 64 + 255) / 256;
        matmul_fallback<<<blocks_mm, 256, 0, stream>>>(outA, outB, Wsrc, Wdst, bsrc, bdst);
    }
}